// Round 1
// baseline (369.545 us; speedup 1.0000x reference)
//
#include <hip/hip_runtime.h>
#include <cstdint>
#include <cstddef>

#define NBUCKET 4096
#define HTHREADS 1024
#define MAXHBLOCKS 256

struct Scalars {
  unsigned long long b1;
  unsigned long long above_cnt1;
  double sum_hi;
};

__device__ __forceinline__ float bce_loss(float x, float t) {
  // numerically stable BCE-with-logits: max(x,0) - x*t + log1p(exp(-|x|))
  return fmaxf(x, 0.0f) - x * t + log1pf(expf(-fabsf(x)));
}

// ---------------- Pass 1: coarse histogram on top 12 bits ----------------
__global__ __launch_bounds__(HTHREADS) void hist1_kernel(
    const float* __restrict__ pred, const float* __restrict__ targ,
    unsigned int N, unsigned int* __restrict__ partials) {
  __shared__ unsigned int h[4][NBUCKET];  // 4 replicas vs LDS atomic serialization
  int tid = threadIdx.x;
  for (int i = tid; i < 4 * NBUCKET; i += HTHREADS) ((unsigned int*)h)[i] = 0u;
  __syncthreads();
  unsigned int* hh = h[(tid >> 6) & 3];
  unsigned int n4 = N >> 2;
  const float4* p4 = (const float4*)pred;
  const float4* t4 = (const float4*)targ;
  unsigned int stride = gridDim.x * blockDim.x;
  for (unsigned int i = blockIdx.x * blockDim.x + tid; i < n4; i += stride) {
    float4 x = p4[i];
    float4 t = t4[i];
    unsigned int b;
    b = __float_as_uint(bce_loss(x.x, t.x)) >> 20; atomicAdd(&hh[b], 1u);
    b = __float_as_uint(bce_loss(x.y, t.y)) >> 20; atomicAdd(&hh[b], 1u);
    b = __float_as_uint(bce_loss(x.z, t.z)) >> 20; atomicAdd(&hh[b], 1u);
    b = __float_as_uint(bce_loss(x.w, t.w)) >> 20; atomicAdd(&hh[b], 1u);
  }
  if (blockIdx.x == 0) {  // tail (N % 4)
    for (unsigned int i = (n4 << 2) + tid; i < N; i += HTHREADS) {
      unsigned int b = __float_as_uint(bce_loss(pred[i], targ[i])) >> 20;
      atomicAdd(&hh[b], 1u);
    }
  }
  __syncthreads();
  unsigned int* out = partials + (size_t)blockIdx.x * NBUCKET;
  for (int i = tid; i < NBUCKET; i += HTHREADS)
    out[i] = h[0][i] + h[1][i] + h[2][i] + h[3][i];
}

// ---------------- Reduce per-block partials to final hist (+sums) --------
__global__ void reduce_kernel(const unsigned int* __restrict__ pcnt,
                              const float* __restrict__ psum, int nblocks,
                              unsigned int* __restrict__ histf,
                              double* __restrict__ sumsf, int use_sums) {
  int b = blockIdx.x * blockDim.x + threadIdx.x;
  if (b >= NBUCKET) return;
  unsigned long long c = 0;
  double s = 0.0;
  for (int j = 0; j < nblocks; j++) {
    c += pcnt[(size_t)j * NBUCKET + b];
    if (use_sums) s += (double)psum[(size_t)j * NBUCKET + b];
  }
  histf[b] = (unsigned int)c;
  if (use_sums) sumsf[b] = s;
}

// ---------------- Scan 1: find coarse threshold bucket b1 ----------------
__global__ __launch_bounds__(1024) void scan1_kernel(
    const unsigned int* __restrict__ histf, unsigned long long K,
    Scalars* __restrict__ sc) {
  __shared__ unsigned long long cs[1024];
  int tid = threadIdx.x;
  unsigned int c[4];
#pragma unroll
  for (int j = 0; j < 4; j++) c[j] = histf[4 * tid + j];
  unsigned long long my = (unsigned long long)c[0] + c[1] + c[2] + c[3];
  cs[tid] = my;
  __syncthreads();
  for (int off = 1; off < 1024; off <<= 1) {
    unsigned long long t = (tid + off < 1024) ? cs[tid + off] : 0ULL;
    __syncthreads();
    cs[tid] += t;
    __syncthreads();
  }
  unsigned long long ab = (tid < 1023) ? cs[tid + 1] : 0ULL;  // count strictly above
  for (int j = 3; j >= 0; j--) {
    unsigned long long ge = ab + c[j];
    if (ab < K && ge >= K) {  // exactly one bucket satisfies
      sc->b1 = (unsigned long long)(4 * tid + j);
      sc->above_cnt1 = ab;
      sc->sum_hi = 0.0;  // zero accumulator for pass 2
    }
    ab = ge;
  }
}

// ---------------- Pass 2: sum above b1; refine inside b1 -----------------
__global__ __launch_bounds__(HTHREADS) void pass2_kernel(
    const float* __restrict__ pred, const float* __restrict__ targ,
    unsigned int N, Scalars* __restrict__ sc, unsigned int* __restrict__ pcnt,
    float* __restrict__ psum) {
  __shared__ unsigned int h[2][NBUCKET];
  __shared__ float s[2][NBUCKET];
  __shared__ double wsum[HTHREADS / 64];
  int tid = threadIdx.x;
  for (int i = tid; i < 2 * NBUCKET; i += HTHREADS) {
    ((unsigned int*)h)[i] = 0u;
    ((float*)s)[i] = 0.0f;
  }
  __syncthreads();
  int cp = (tid >> 6) & 1;
  unsigned int b1 = (unsigned int)sc->b1;
  double local = 0.0;
  unsigned int n4 = N >> 2;
  const float4* p4 = (const float4*)pred;
  const float4* t4 = (const float4*)targ;
  unsigned int stride = gridDim.x * blockDim.x;
  for (unsigned int i = blockIdx.x * blockDim.x + tid; i < n4; i += stride) {
    float4 x = p4[i];
    float4 t = t4[i];
    float l;
    unsigned int bits, b;
#define P2(c0, c1)                                             \
    l = bce_loss(x.c0, t.c1);                                  \
    bits = __float_as_uint(l);                                 \
    b = bits >> 20;                                            \
    if (b > b1) local += (double)l;                            \
    else if (b == b1) {                                        \
      unsigned int sb = (bits >> 8) & 0xFFFu;                  \
      atomicAdd(&h[cp][sb], 1u);                               \
      atomicAdd(&s[cp][sb], l);                                \
    }
    P2(x, x) P2(y, y) P2(z, z) P2(w, w)
#undef P2
  }
  if (blockIdx.x == 0) {  // tail
    for (unsigned int i = (n4 << 2) + tid; i < N; i += HTHREADS) {
      float l = bce_loss(pred[i], targ[i]);
      unsigned int bits = __float_as_uint(l);
      unsigned int b = bits >> 20;
      if (b > b1) local += (double)l;
      else if (b == b1) {
        unsigned int sb = (bits >> 8) & 0xFFFu;
        atomicAdd(&h[cp][sb], 1u);
        atomicAdd(&s[cp][sb], l);
      }
    }
  }
  __syncthreads();
  unsigned int* oc = pcnt + (size_t)blockIdx.x * NBUCKET;
  float* os = psum + (size_t)blockIdx.x * NBUCKET;
  for (int i = tid; i < NBUCKET; i += HTHREADS) {
    oc[i] = h[0][i] + h[1][i];
    os[i] = s[0][i] + s[1][i];
  }
  // block-reduce the "strictly above b1" partial sum
  for (int off = 32; off > 0; off >>= 1) local += __shfl_down(local, off, 64);
  if ((tid & 63) == 0) wsum[tid >> 6] = local;
  __syncthreads();
  if (tid == 0) {
    double tot = 0.0;
    for (int w = 0; w < HTHREADS / 64; w++) tot += wsum[w];
    atomicAdd(&sc->sum_hi, tot);
  }
}

// ---------------- Scan 2: refine, assemble final mean --------------------
__global__ __launch_bounds__(1024) void scan2_kernel(
    const unsigned int* __restrict__ histf, const double* __restrict__ sumsf,
    unsigned long long K, const Scalars* __restrict__ sc,
    float* __restrict__ out) {
  __shared__ unsigned long long cs[1024];
  __shared__ double ss[1024];
  int tid = threadIdx.x;
  unsigned int c[4];
  double v[4];
#pragma unroll
  for (int j = 0; j < 4; j++) {
    c[j] = histf[4 * tid + j];
    v[j] = sumsf[4 * tid + j];
  }
  unsigned long long my = (unsigned long long)c[0] + c[1] + c[2] + c[3];
  double ms = v[0] + v[1] + v[2] + v[3];
  cs[tid] = my;
  ss[tid] = ms;
  __syncthreads();
  for (int off = 1; off < 1024; off <<= 1) {
    unsigned long long t = (tid + off < 1024) ? cs[tid + off] : 0ULL;
    double td = (tid + off < 1024) ? ss[tid + off] : 0.0;
    __syncthreads();
    cs[tid] += t;
    ss[tid] += td;
    __syncthreads();
  }
  unsigned long long ab = (tid < 1023) ? cs[tid + 1] : 0ULL;
  double abv = (tid < 1023) ? ss[tid + 1] : 0.0;
  unsigned long long kp = K - sc->above_cnt1;  // elements still needed from b1
  for (int j = 3; j >= 0; j--) {
    unsigned long long ge = ab + c[j];
    if (ab < kp && ge >= kp) {
      unsigned long long rem = kp - ab;
      double avg = v[j] / (double)c[j];  // tie bucket: spread < 2^-15 relative
      double total = sc->sum_hi + abv + (double)rem * avg;
      *out = (float)(total / (double)K);
    }
    ab = ge;
    abv += v[j];
  }
}

extern "C" void kernel_launch(void* const* d_in, const int* in_sizes, int n_in,
                              void* d_out, int out_size, void* d_ws,
                              size_t ws_size, hipStream_t stream) {
  const float* pred = (const float*)d_in[0];
  const float* targ = (const float*)d_in[1];
  unsigned int N = (unsigned int)in_sizes[0];
  unsigned long long K = (unsigned long long)(0.25 * (double)N);
  if (K < 1) K = 1;

  // workspace layout (sized to fit ws_size): [pcnt | psum | histf | sumsf | scalars]
  size_t fixed = (size_t)NBUCKET * 4 + (size_t)NBUCKET * 8 + 256;
  int nb = MAXHBLOCKS;
  if (ws_size > fixed) {
    size_t cap = (ws_size - fixed) / ((size_t)NBUCKET * 8);
    if ((size_t)nb > cap) nb = (int)cap;
  } else {
    nb = 1;
  }
  if (nb < 1) nb = 1;

  char* ws = (char*)d_ws;
  unsigned int* pcnt = (unsigned int*)ws;
  float* psum = (float*)(ws + (size_t)nb * NBUCKET * 4);
  char* tail = ws + (size_t)nb * NBUCKET * 8;
  unsigned int* histf = (unsigned int*)tail;
  double* sumsf = (double*)(tail + (size_t)NBUCKET * 4);
  Scalars* sc = (Scalars*)(tail + (size_t)NBUCKET * 4 + (size_t)NBUCKET * 8);

  float* out = (float*)d_out;

  hist1_kernel<<<nb, HTHREADS, 0, stream>>>(pred, targ, N, pcnt);
  reduce_kernel<<<(NBUCKET + 63) / 64, 64, 0, stream>>>(pcnt, psum, nb, histf,
                                                        sumsf, 0);
  scan1_kernel<<<1, 1024, 0, stream>>>(histf, K, sc);
  pass2_kernel<<<nb, HTHREADS, 0, stream>>>(pred, targ, N, sc, pcnt, psum);
  reduce_kernel<<<(NBUCKET + 63) / 64, 64, 0, stream>>>(pcnt, psum, nb, histf,
                                                        sumsf, 1);
  scan2_kernel<<<1, 1024, 0, stream>>>(histf, sumsf, K, sc, out);
}

// Round 2
// 182.301 us; speedup vs baseline: 2.0271x; 2.0271x over previous
//
#include <hip/hip_runtime.h>
#include <cstdint>
#include <cstddef>

#define NBUCKET 4096
#define HTHREADS 1024
#define NBLOCKS 512

struct Scalars {
  unsigned long long b1;
  unsigned long long above_cnt1;
  double sum_hi;
};

__device__ __forceinline__ float bce_loss(float x, float t) {
  // numerically stable BCE-with-logits: max(x,0) - x*t + log1p(exp(-|x|))
  // fast path: v_exp_f32 / v_log_f32 (abs err ~1e-6, fine vs 2.5e-2 threshold;
  // both passes use this identical function so bucket bits are consistent)
  float u = __expf(-fabsf(x));
  return fmaxf(x, 0.0f) - x * t + __logf(1.0f + u);
}

// ---------------- init: zero the global histograms -----------------------
__global__ void init_kernel(unsigned int* __restrict__ z, int n) {
  int i = blockIdx.x * blockDim.x + threadIdx.x;
  if (i < n) z[i] = 0u;
}

// ---------------- Pass 1: coarse histogram on top 12 bits ----------------
__global__ __launch_bounds__(HTHREADS) void hist1_kernel(
    const float* __restrict__ pred, const float* __restrict__ targ,
    unsigned int N, unsigned int* __restrict__ histf) {
  __shared__ unsigned int h[4][NBUCKET];  // 4 replicas vs LDS atomic serialization
  int tid = threadIdx.x;
  for (int i = tid; i < 4 * NBUCKET; i += HTHREADS) ((unsigned int*)h)[i] = 0u;
  __syncthreads();
  unsigned int* hh = h[(tid >> 6) & 3];
  unsigned int n4 = N >> 2;
  const float4* p4 = (const float4*)pred;
  const float4* t4 = (const float4*)targ;
  unsigned int stride = gridDim.x * blockDim.x;
  for (unsigned int i = blockIdx.x * blockDim.x + tid; i < n4; i += stride) {
    float4 x = p4[i];
    float4 t = t4[i];
    unsigned int b;
    b = __float_as_uint(bce_loss(x.x, t.x)) >> 20; atomicAdd(&hh[b], 1u);
    b = __float_as_uint(bce_loss(x.y, t.y)) >> 20; atomicAdd(&hh[b], 1u);
    b = __float_as_uint(bce_loss(x.z, t.z)) >> 20; atomicAdd(&hh[b], 1u);
    b = __float_as_uint(bce_loss(x.w, t.w)) >> 20; atomicAdd(&hh[b], 1u);
  }
  if (blockIdx.x == 0) {  // tail (N % 4)
    for (unsigned int i = (n4 << 2) + tid; i < N; i += HTHREADS) {
      unsigned int b = __float_as_uint(bce_loss(pred[i], targ[i])) >> 20;
      atomicAdd(&hh[b], 1u);
    }
  }
  __syncthreads();
  // only ~150 buckets are nonzero (exponent-concentrated) -> cheap global atomics
  for (int i = tid; i < NBUCKET; i += HTHREADS) {
    unsigned int v = h[0][i] + h[1][i] + h[2][i] + h[3][i];
    if (v) atomicAdd(&histf[i], v);
  }
}

// ---------------- Scan 1: find coarse threshold bucket b1 ----------------
__global__ __launch_bounds__(1024) void scan1_kernel(
    const unsigned int* __restrict__ histf, unsigned long long K,
    Scalars* __restrict__ sc) {
  __shared__ unsigned long long cs[1024];
  int tid = threadIdx.x;
  unsigned int c[4];
#pragma unroll
  for (int j = 0; j < 4; j++) c[j] = histf[4 * tid + j];
  unsigned long long my = (unsigned long long)c[0] + c[1] + c[2] + c[3];
  cs[tid] = my;
  __syncthreads();
  for (int off = 1; off < 1024; off <<= 1) {
    unsigned long long t = (tid + off < 1024) ? cs[tid + off] : 0ULL;
    __syncthreads();
    cs[tid] += t;
    __syncthreads();
  }
  unsigned long long ab = (tid < 1023) ? cs[tid + 1] : 0ULL;  // count strictly above
  for (int j = 3; j >= 0; j--) {
    unsigned long long ge = ab + c[j];
    if (ab < K && ge >= K) {  // exactly one bucket satisfies
      sc->b1 = (unsigned long long)(4 * tid + j);
      sc->above_cnt1 = ab;
      sc->sum_hi = 0.0;  // zero accumulator for pass 2
    }
    ab = ge;
  }
}

// ---------------- Pass 2: sum above b1; refine inside b1 -----------------
__global__ __launch_bounds__(HTHREADS) void pass2_kernel(
    const float* __restrict__ pred, const float* __restrict__ targ,
    unsigned int N, Scalars* __restrict__ sc,
    unsigned int* __restrict__ histf2, float* __restrict__ sumsf2) {
  __shared__ unsigned int h[2][NBUCKET];
  __shared__ float s[2][NBUCKET];
  __shared__ double wsum[HTHREADS / 64];
  int tid = threadIdx.x;
  for (int i = tid; i < 2 * NBUCKET; i += HTHREADS) {
    ((unsigned int*)h)[i] = 0u;
    ((float*)s)[i] = 0.0f;
  }
  __syncthreads();
  int cp = (tid >> 6) & 1;
  unsigned int b1 = (unsigned int)sc->b1;
  double local = 0.0;
  unsigned int n4 = N >> 2;
  const float4* p4 = (const float4*)pred;
  const float4* t4 = (const float4*)targ;
  unsigned int stride = gridDim.x * blockDim.x;
  for (unsigned int i = blockIdx.x * blockDim.x + tid; i < n4; i += stride) {
    float4 x = p4[i];
    float4 t = t4[i];
    float l;
    unsigned int bits, b;
#define P2(c0, c1)                                             \
    l = bce_loss(x.c0, t.c1);                                  \
    bits = __float_as_uint(l);                                 \
    b = bits >> 20;                                            \
    if (b > b1) local += (double)l;                            \
    else if (b == b1) {                                        \
      unsigned int sb = (bits >> 8) & 0xFFFu;                  \
      atomicAdd(&h[cp][sb], 1u);                               \
      atomicAdd(&s[cp][sb], l);                                \
    }
    P2(x, x) P2(y, y) P2(z, z) P2(w, w)
#undef P2
  }
  if (blockIdx.x == 0) {  // tail
    for (unsigned int i = (n4 << 2) + tid; i < N; i += HTHREADS) {
      float l = bce_loss(pred[i], targ[i]);
      unsigned int bits = __float_as_uint(l);
      unsigned int b = bits >> 20;
      if (b > b1) local += (double)l;
      else if (b == b1) {
        unsigned int sb = (bits >> 8) & 0xFFFu;
        atomicAdd(&h[cp][sb], 1u);
        atomicAdd(&s[cp][sb], l);
      }
    }
  }
  __syncthreads();
  for (int i = tid; i < NBUCKET; i += HTHREADS) {
    unsigned int c = h[0][i] + h[1][i];
    float sv = s[0][i] + s[1][i];
    if (c) {
      atomicAdd(&histf2[i], c);
      atomicAdd(&sumsf2[i], sv);
    }
  }
  // block-reduce the "strictly above b1" partial sum
  for (int off = 32; off > 0; off >>= 1) local += __shfl_down(local, off, 64);
  if ((tid & 63) == 0) wsum[tid >> 6] = local;
  __syncthreads();
  if (tid == 0) {
    double tot = 0.0;
    for (int w = 0; w < HTHREADS / 64; w++) tot += wsum[w];
    atomicAdd(&sc->sum_hi, tot);
  }
}

// ---------------- Scan 2: refine, assemble final mean --------------------
__global__ __launch_bounds__(1024) void scan2_kernel(
    const unsigned int* __restrict__ histf2, const float* __restrict__ sumsf2,
    unsigned long long K, const Scalars* __restrict__ sc,
    float* __restrict__ out) {
  __shared__ unsigned long long cs[1024];
  __shared__ double ss[1024];
  int tid = threadIdx.x;
  unsigned int c[4];
  double v[4];
#pragma unroll
  for (int j = 0; j < 4; j++) {
    c[j] = histf2[4 * tid + j];
    v[j] = (double)sumsf2[4 * tid + j];
  }
  unsigned long long my = (unsigned long long)c[0] + c[1] + c[2] + c[3];
  double ms = v[0] + v[1] + v[2] + v[3];
  cs[tid] = my;
  ss[tid] = ms;
  __syncthreads();
  for (int off = 1; off < 1024; off <<= 1) {
    unsigned long long t = (tid + off < 1024) ? cs[tid + off] : 0ULL;
    double td = (tid + off < 1024) ? ss[tid + off] : 0.0;
    __syncthreads();
    cs[tid] += t;
    ss[tid] += td;
    __syncthreads();
  }
  unsigned long long ab = (tid < 1023) ? cs[tid + 1] : 0ULL;
  double abv = (tid < 1023) ? ss[tid + 1] : 0.0;
  unsigned long long kp = K - sc->above_cnt1;  // elements still needed from b1
  for (int j = 3; j >= 0; j--) {
    unsigned long long ge = ab + c[j];
    if (ab < kp && ge >= kp) {
      unsigned long long rem = kp - ab;
      double avg = v[j] / (double)c[j];  // tie bucket: spread < 2^-15 relative
      double total = sc->sum_hi + abv + (double)rem * avg;
      *out = (float)(total / (double)K);
    }
    ab = ge;
    abv += v[j];
  }
}

extern "C" void kernel_launch(void* const* d_in, const int* in_sizes, int n_in,
                              void* d_out, int out_size, void* d_ws,
                              size_t ws_size, hipStream_t stream) {
  const float* pred = (const float*)d_in[0];
  const float* targ = (const float*)d_in[1];
  unsigned int N = (unsigned int)in_sizes[0];
  unsigned long long K = (unsigned long long)(0.25 * (double)N);
  if (K < 1) K = 1;

  // workspace layout: [histf (16KB) | histf2 (16KB) | sumsf2 (16KB) | Scalars]
  char* ws = (char*)d_ws;
  unsigned int* histf = (unsigned int*)ws;
  unsigned int* histf2 = (unsigned int*)(ws + (size_t)NBUCKET * 4);
  float* sumsf2 = (float*)(ws + (size_t)NBUCKET * 8);
  Scalars* sc = (Scalars*)(ws + (size_t)NBUCKET * 12);

  float* out = (float*)d_out;

  int zwords = 3 * NBUCKET;
  init_kernel<<<(zwords + 1023) / 1024, 1024, 0, stream>>>(histf, zwords);
  hist1_kernel<<<NBLOCKS, HTHREADS, 0, stream>>>(pred, targ, N, histf);
  scan1_kernel<<<1, 1024, 0, stream>>>(histf, K, sc);
  pass2_kernel<<<NBLOCKS, HTHREADS, 0, stream>>>(pred, targ, N, sc, histf2,
                                                 sumsf2);
  scan2_kernel<<<1, 1024, 0, stream>>>(histf2, sumsf2, K, sc, out);
}

// Round 4
// 148.947 us; speedup vs baseline: 2.4810x; 1.2239x over previous
//
#include <hip/hip_runtime.h>
#include <cstdint>
#include <cstddef>

#define NB 8192        // buckets: loss>=0 so bits>>18 = 0+exp(8)+5 mantissa bits
#define TH 1024
#define GRID 512       // 2 blocks/CU * 256 CU

__device__ __forceinline__ float bce_loss(float x, float t) {
  // stable BCE-with-logits, fast transcendentals (err ~1e-6 << 2.5e-2 threshold)
  float u = __expf(-fabsf(x));
  return fmaxf(x, 0.0f) - x * t + __logf(1.0f + u);
}

__device__ __forceinline__ float bucket_mid(unsigned int b) {
  // arithmetic midpoint of bucket [b<<18, (b+1)<<18).
  // NOTE: for b >= 8160 this bit pattern is Inf/NaN — callers must only use it
  // for buckets with nonzero count (real losses are finite, <~6).
  return __uint_as_float((b << 18) | 0x20000u);
}

// ---------------- zero the global histogram ------------------------------
__global__ void init_kernel(unsigned int* __restrict__ z) {
  z[blockIdx.x * 1024 + threadIdx.x] = 0u;
}

// ---------------- single pass: count-only histogram on bits>>18 ----------
__global__ __launch_bounds__(TH) void hist_kernel(
    const float* __restrict__ pred, const float* __restrict__ targ,
    unsigned int N, unsigned int* __restrict__ hist) {
  __shared__ unsigned int h[2][NB];  // 2 replicas: halves same-address pressure
  int tid = threadIdx.x;
  for (int i = tid; i < 2 * NB; i += TH) ((unsigned int*)h)[i] = 0u;
  __syncthreads();
  unsigned int* hh = h[(tid >> 6) & 1];
  unsigned int n4 = N >> 2;
  const float4* p4 = (const float4*)pred;
  const float4* t4 = (const float4*)targ;
  unsigned int stride = gridDim.x * blockDim.x;
  for (unsigned int i = blockIdx.x * blockDim.x + tid; i < n4; i += stride) {
    float4 x = p4[i];
    float4 t = t4[i];
    float l;
    unsigned int b;
    // clamp: loss is mathematically > 0; guard fast-math edge to keep sign=0
    l = fmaxf(bce_loss(x.x, t.x), 0.0f); b = __float_as_uint(l) >> 18; atomicAdd(&hh[b], 1u);
    l = fmaxf(bce_loss(x.y, t.y), 0.0f); b = __float_as_uint(l) >> 18; atomicAdd(&hh[b], 1u);
    l = fmaxf(bce_loss(x.z, t.z), 0.0f); b = __float_as_uint(l) >> 18; atomicAdd(&hh[b], 1u);
    l = fmaxf(bce_loss(x.w, t.w), 0.0f); b = __float_as_uint(l) >> 18; atomicAdd(&hh[b], 1u);
  }
  if (blockIdx.x == 0) {  // tail (N % 4)
    for (unsigned int i = (n4 << 2) + tid; i < N; i += TH) {
      float l = fmaxf(bce_loss(pred[i], targ[i]), 0.0f);
      atomicAdd(&hh[__float_as_uint(l) >> 18], 1u);
    }
  }
  __syncthreads();
  // ~400 nonzero buckets/block -> cheap global flush
  for (int i = tid; i < NB; i += TH) {
    unsigned int v = h[0][i] + h[1][i];
    if (v) atomicAdd(&hist[i], v);
  }
}

// ---------------- scan: suffix sums, find threshold, emit mean -----------
__global__ __launch_bounds__(512) void scan_kernel(
    const unsigned int* __restrict__ hist, unsigned long long K,
    float* __restrict__ out) {
  __shared__ unsigned long long cs[512];
  __shared__ double ss[512];
  int tid = threadIdx.x;  // 512 threads * 16 buckets = 8192
  unsigned int c[16];
  unsigned long long cnt = 0;
  double wsum = 0.0;
#pragma unroll
  for (int j = 0; j < 16; j++) {
    c[j] = hist[16 * tid + j];
    cnt += c[j];
    // guard: bucket_mid of empty high buckets is Inf/NaN; 0*NaN would poison
    if (c[j]) wsum += (double)c[j] * (double)bucket_mid(16 * tid + j);
  }
  cs[tid] = cnt;
  ss[tid] = wsum;
  __syncthreads();
  // inclusive suffix sum over threads
  for (int off = 1; off < 512; off <<= 1) {
    unsigned long long t = (tid + off < 512) ? cs[tid + off] : 0ULL;
    double td = (tid + off < 512) ? ss[tid + off] : 0.0;
    __syncthreads();
    cs[tid] += t;
    ss[tid] += td;
    __syncthreads();
  }
  unsigned long long ab = (tid < 511) ? cs[tid + 1] : 0ULL;   // strictly above my range
  double wab = (tid < 511) ? ss[tid + 1] : 0.0;
  for (int j = 15; j >= 0; j--) {
    unsigned long long ge = ab + c[j];
    if (ab < K && ge >= K) {  // exactly one (tid,j) satisfies; c[j] >= 1 here
      unsigned long long rem = K - ab;
      double total = wab + (double)rem * (double)bucket_mid(16 * tid + j);
      *out = (float)(total / (double)K);
    }
    ab = ge;
    if (c[j]) wab += (double)c[j] * (double)bucket_mid(16 * tid + j);
  }
}

extern "C" void kernel_launch(void* const* d_in, const int* in_sizes, int n_in,
                              void* d_out, int out_size, void* d_ws,
                              size_t ws_size, hipStream_t stream) {
  const float* pred = (const float*)d_in[0];
  const float* targ = (const float*)d_in[1];
  unsigned int N = (unsigned int)in_sizes[0];
  unsigned long long K = (unsigned long long)(0.25 * (double)N);
  if (K < 1) K = 1;

  unsigned int* hist = (unsigned int*)d_ws;  // 32 KB
  float* out = (float*)d_out;

  init_kernel<<<NB / 1024, 1024, 0, stream>>>(hist);
  hist_kernel<<<GRID, TH, 0, stream>>>(pred, targ, N, hist);
  scan_kernel<<<1, 512, 0, stream>>>(hist, K, out);
}